// Round 1
// baseline (1261.674 us; speedup 1.0000x reference)
//
#include <hip/hip_runtime.h>

// DoubleKVCache: B=2, H=32, S_MAX=8192, D=128, S_NEW=in_sizes[0] (512)
// Outputs (f32, concat): out0 = kt_cache^T with scatter  [B,H,S_MAX,D]
//                        out1 = k_cache  with scatter    [B,H,S_MAX,D]
//                        out2 = v_cache  with scatter    [B,H,S_MAX,D]

#define S_MAXC 8192
#define DC     128
#define BHC    64   // B*H

__global__ void init_inv(int* __restrict__ inv) {
    int i = blockIdx.x * blockDim.x + threadIdx.x;
    if (i < S_MAXC) inv[i] = -1;
}

__global__ void scatter_inv(const int* __restrict__ pos, int* __restrict__ inv, int n) {
    int j = blockIdx.x * blockDim.x + threadIdx.x;
    if (j < n) inv[pos[j]] = j;
}

// out1/out2: straight float4 copy with per-row scatter select.
// One float4 of K-output and one of V-output per thread.
__global__ void __launch_bounds__(256) copy_scatter(
        const float4* __restrict__ k_val,   // [BH][S_NEW][32]
        const float4* __restrict__ v_val,
        const float4* __restrict__ k_cache, // [BH][S_MAX][32]
        const float4* __restrict__ v_cache,
        const int*    __restrict__ inv,
        float4* __restrict__ out_k,
        float4* __restrict__ out_v,
        int s_new) {
    long i = (long)blockIdx.x * blockDim.x + threadIdx.x;   // float4 index
    int d4 = (int)(i & 31);
    int s  = (int)((i >> 5) & (S_MAXC - 1));
    int bh = (int)(i >> 18);                                // /(32*8192)
    int j = inv[s];
    if (j >= 0) {
        long src = ((long)bh * s_new + j) * 32 + d4;
        out_k[i] = k_val[src];
        out_v[i] = v_val[src];
    } else {
        out_k[i] = k_cache[i];
        out_v[i] = v_cache[i];
    }
}

// out0[bh][s][d] = kt_cache[bh][d][s] (or k_val row if s is scattered).
// Tile: full D=128 x 32 s-positions, staged through LDS.
__global__ void __launch_bounds__(256) transpose_kt(
        const float*  __restrict__ kt_cache, // [BH][D][S_MAX]
        const float4* __restrict__ k_val,    // [BH][S_NEW][32]
        const int*    __restrict__ inv,
        float4* __restrict__ out0,           // [BH][S_MAX][32]
        int s_new) {
    __shared__ __align__(16) float tile[32][132]; // [s_local][d], pad 132: 528B rows, 16B-aligned
    const int bh = blockIdx.y;
    const int s0 = blockIdx.x * 32;
    const int t  = threadIdx.x;
    const int q  = t & 7;    // 0..7
    const int r  = t >> 3;   // 0..31

    const float* ktb = kt_cache + (long)bh * DC * S_MAXC;
    // Load 128x32 tile: lane group of 8 reads one d-row, float4 along s (coalesced 128B segments)
    #pragma unroll
    for (int p = 0; p < 4; ++p) {
        int d = p * 32 + r;
        float4 vld = *(const float4*)(ktb + (long)d * S_MAXC + s0 + 4 * q);
        tile[4 * q + 0][d] = vld.x;
        tile[4 * q + 1][d] = vld.y;
        tile[4 * q + 2][d] = vld.z;
        tile[4 * q + 3][d] = vld.w;
    }
    __syncthreads();

    // Write: 8 threads per output row s, 4 float4 each (fully coalesced 512B rows)
    const int sl = r;
    const int s  = s0 + sl;
    const int j  = inv[s];
    float4* outrow = out0 + ((long)bh * S_MAXC + s) * 32;
    if (j >= 0) {
        const float4* src = k_val + ((long)bh * s_new + j) * 32;
        #pragma unroll
        for (int m = 0; m < 4; ++m)
            outrow[q + 8 * m] = src[q + 8 * m];
    } else {
        #pragma unroll
        for (int m = 0; m < 4; ++m) {
            int dd = 4 * (q + 8 * m);
            outrow[q + 8 * m] = *(const float4*)&tile[sl][dd];
        }
    }
}

extern "C" void kernel_launch(void* const* d_in, const int* in_sizes, int n_in,
                              void* d_out, int out_size, void* d_ws, size_t ws_size,
                              hipStream_t stream) {
    const int*   input_pos = (const int*)  d_in[0];
    const float* k_val     = (const float*)d_in[1];
    const float* v_val     = (const float*)d_in[2];
    const float* k_cache   = (const float*)d_in[3];
    const float* kt_cache  = (const float*)d_in[4];
    const float* v_cache   = (const float*)d_in[5];
    const int s_new = in_sizes[0];

    const long per_out = (long)BHC * S_MAXC * DC;   // 67,108,864 floats
    float* out0 = (float*)d_out;                    // kt^T
    float* out1 = out0 + per_out;                   // k
    float* out2 = out1 + per_out;                   // v

    int* inv = (int*)d_ws;                          // 8192 ints (d_ws re-poisoned each call)

    init_inv<<<S_MAXC / 256, 256, 0, stream>>>(inv);
    scatter_inv<<<(s_new + 255) / 256, 256, 0, stream>>>(input_pos, inv, s_new);

    const long total4 = per_out / 4;                // 16,777,216 float4 per tensor
    copy_scatter<<<(int)(total4 / 256), 256, 0, stream>>>(
        (const float4*)k_val, (const float4*)v_val,
        (const float4*)k_cache, (const float4*)v_cache, inv,
        (float4*)out1, (float4*)out2, s_new);

    dim3 grid_t(S_MAXC / 32, BHC);
    transpose_kt<<<grid_t, 256, 0, stream>>>(
        kt_cache, (const float4*)k_val, inv, (float4*)out0, s_new);
}

// Round 2
// 1255.133 us; speedup vs baseline: 1.0052x; 1.0052x over previous
//
#include <hip/hip_runtime.h>

// DoubleKVCache: B=2, H=32, S_MAX=8192, D=128, S_NEW=in_sizes[0] (512)
// Outputs (f32, concat): out0 = kt_cache^T with scatter  [B,H,S_MAX,D]
//                        out1 = k_cache  with scatter    [B,H,S_MAX,D]
//                        out2 = v_cache  with scatter    [B,H,S_MAX,D]
// Fused single-pass kernel: one block per (bh, 32-row s-tile) writes all
// three outputs. Non-temporal loads/stores for all streamed (use-once)
// traffic to keep L2 from thrashing on 1.6 GB of streams.

#define S_MAXC 8192
#define DC     128
#define BHC    64   // B*H

typedef __attribute__((ext_vector_type(4))) float v4f;

__global__ void init_inv(int* __restrict__ inv) {
    int i = blockIdx.x * blockDim.x + threadIdx.x;
    if (i < S_MAXC) inv[i] = -1;
}

__global__ void scatter_inv(const int* __restrict__ pos, int* __restrict__ inv, int n) {
    int j = blockIdx.x * blockDim.x + threadIdx.x;
    if (j < n) inv[pos[j]] = j;
}

__global__ void __launch_bounds__(256) fused_kv(
        const v4f* __restrict__ k_val,    // [BH][S_NEW][32]
        const v4f* __restrict__ v_val,
        const v4f* __restrict__ k_cache,  // [BH][S_MAX][32]
        const v4f* __restrict__ v_cache,
        const float* __restrict__ kt_cache, // [BH][D][S_MAX]
        const int*  __restrict__ inv,
        v4f* __restrict__ out0,
        v4f* __restrict__ out1,
        v4f* __restrict__ out2,
        int s_new) {
    __shared__ __align__(16) float tile[32][132]; // [s_local][d], pad 132
    const int tid = blockIdx.x;      // 0..16383
    const int bh  = tid >> 8;        // 256 s-tiles per bh
    const int s0  = (tid & 255) << 5;
    const int t   = threadIdx.x;
    const int q   = t & 7;           // 0..7
    const int r   = t >> 3;          // 0..31

    // Phase A: stage the 128(d) x 32(s) kt tile into LDS, transposing.
    // Group of 8 lanes reads one d-row as a v4f along s (128B segments).
    const float* ktb = kt_cache + (long)bh * DC * S_MAXC;
    #pragma unroll
    for (int p = 0; p < 4; ++p) {
        int d = p * 32 + r;
        v4f vld = __builtin_nontemporal_load(
            (const v4f*)(ktb + (long)d * S_MAXC + s0 + 4 * q));
        tile[4 * q + 0][d] = vld.x;
        tile[4 * q + 1][d] = vld.y;
        tile[4 * q + 2][d] = vld.z;
        tile[4 * q + 3][d] = vld.w;
    }
    __syncthreads();

    // Phase B: 8 lanes per output row s = s0 + r, 4 v4f each per tensor.
    const int s = s0 + r;
    const int j = inv[s];
    const long row = (long)bh * S_MAXC + s;
    v4f* o0 = out0 + row * 32;
    v4f* o1 = out1 + row * 32;
    v4f* o2 = out2 + row * 32;
    if (j >= 0) {
        // Scattered row: out0 row == out1 row == k_val row; out2 = v_val row.
        const v4f* kv = k_val + ((long)bh * s_new + j) * 32;
        const v4f* vv = v_val + ((long)bh * s_new + j) * 32;
        #pragma unroll
        for (int m = 0; m < 4; ++m) {
            int c = q + 8 * m;
            v4f kx = kv[c];
            v4f vx = vv[c];
            __builtin_nontemporal_store(kx, o0 + c);
            __builtin_nontemporal_store(kx, o1 + c);
            __builtin_nontemporal_store(vx, o2 + c);
        }
    } else {
        const v4f* kc = k_cache + row * 32;
        const v4f* vc = v_cache + row * 32;
        #pragma unroll
        for (int m = 0; m < 4; ++m) {
            int c = q + 8 * m;
            v4f kx = __builtin_nontemporal_load(kc + c);
            v4f vx = __builtin_nontemporal_load(vc + c);
            v4f tx = *(const v4f*)&tile[r][4 * c];
            __builtin_nontemporal_store(tx, o0 + c);
            __builtin_nontemporal_store(kx, o1 + c);
            __builtin_nontemporal_store(vx, o2 + c);
        }
    }
}

extern "C" void kernel_launch(void* const* d_in, const int* in_sizes, int n_in,
                              void* d_out, int out_size, void* d_ws, size_t ws_size,
                              hipStream_t stream) {
    const int*   input_pos = (const int*)  d_in[0];
    const float* k_val     = (const float*)d_in[1];
    const float* v_val     = (const float*)d_in[2];
    const float* k_cache   = (const float*)d_in[3];
    const float* kt_cache  = (const float*)d_in[4];
    const float* v_cache   = (const float*)d_in[5];
    const int s_new = in_sizes[0];

    const long per_out = (long)BHC * S_MAXC * DC;   // 67,108,864 floats
    float* out0 = (float*)d_out;                    // kt^T
    float* out1 = out0 + per_out;                   // k
    float* out2 = out1 + per_out;                   // v

    int* inv = (int*)d_ws;  // 8192 ints; d_ws re-poisoned each call, rebuild

    init_inv<<<S_MAXC / 256, 256, 0, stream>>>(inv);
    scatter_inv<<<(s_new + 255) / 256, 256, 0, stream>>>(input_pos, inv, s_new);

    const int n_tiles = BHC * (S_MAXC / 32);        // 16384 blocks
    fused_kv<<<n_tiles, 256, 0, stream>>>(
        (const v4f*)k_val, (const v4f*)v_val,
        (const v4f*)k_cache, (const v4f*)v_cache,
        kt_cache, inv,
        (v4f*)out0, (v4f*)out1, (v4f*)out2, s_new);
}